// Round 1
// baseline (371.319 us; speedup 1.0000x reference)
//
#include <hip/hip_runtime.h>
#include <hip/hip_bf16.h>
#include <math.h>

#define N_NODES 100000
#define N_EDGES 1600000
#define F0 32
#define F1 16
#define F2 8
#define NCLS 6
#define NGRAPH 64

// ---------------- scatter: agg1[dst] += x[src], 32 features ----------------
__global__ void scatter32_k(const float* __restrict__ x,
                            const int* __restrict__ ei,
                            float* __restrict__ agg) {
    int tid = blockIdx.x * blockDim.x + threadIdx.x;
    int e = tid >> 5;          // edge index
    int f = tid & 31;          // feature
    if (e >= N_EDGES) return;
    int src = ei[e];
    int dst = ei[N_EDGES + e];
    atomicAdd(&agg[dst * F0 + f], x[src * F0 + f]);
}

// ---------------- scatter: agg2[dst] += h1[src], 16 features ----------------
__global__ void scatter16_k(const float* __restrict__ h1,
                            const int* __restrict__ ei,
                            float* __restrict__ agg) {
    int tid = blockIdx.x * blockDim.x + threadIdx.x;
    int e = tid >> 4;
    int f = tid & 15;
    if (e >= N_EDGES) return;
    int src = ei[e];
    int dst = ei[N_EDGES + e];
    atomicAdd(&agg[dst * F1 + f], h1[src * F1 + f]);
}

// ---------------- layer-1 MLP: h1 = relu(relu((x+agg1)W1a+b1a)W1b+b1b) ------
__global__ void mlp1_k(const float* __restrict__ x,
                       const float* __restrict__ agg,
                       const float* __restrict__ W1a, const float* __restrict__ b1a,
                       const float* __restrict__ W1b, const float* __restrict__ b1b,
                       float* __restrict__ h1out) {
    __shared__ float sW1a[F0 * F1];
    __shared__ float sW1b[F1 * F1];
    __shared__ float sb1a[F1];
    __shared__ float sb1b[F1];
    int t = threadIdx.x;
    for (int i = t; i < F0 * F1; i += blockDim.x) sW1a[i] = W1a[i];
    for (int i = t; i < F1 * F1; i += blockDim.x) sW1b[i] = W1b[i];
    if (t < F1) { sb1a[t] = b1a[t]; sb1b[t] = b1b[t]; }
    __syncthreads();

    int n = blockIdx.x * blockDim.x + t;
    if (n >= N_NODES) return;

    float h[F0];
#pragma unroll
    for (int k = 0; k < F0; k++) h[k] = x[n * F0 + k] + agg[n * F0 + k];

    float u[F1];
#pragma unroll
    for (int j = 0; j < F1; j++) {
        float s = sb1a[j];
#pragma unroll
        for (int k = 0; k < F0; k++) s += h[k] * sW1a[k * F1 + j];
        u[j] = fmaxf(s, 0.0f);
    }
#pragma unroll
    for (int j = 0; j < F1; j++) {
        float s = sb1b[j];
#pragma unroll
        for (int k = 0; k < F1; k++) s += u[k] * sW1b[k * F1 + j];
        h1out[n * F1 + j] = fmaxf(s, 0.0f);
    }
}

// ------- layer-2 MLP fused with mean-pool accumulation (batch sorted) -------
__global__ void mlp2pool_k(const float* __restrict__ h1,
                           const float* __restrict__ agg2,
                           const float* __restrict__ W2a, const float* __restrict__ b2a,
                           const float* __restrict__ W2b, const float* __restrict__ b2b,
                           const int* __restrict__ batch,
                           float* __restrict__ gsum,   // [NGRAPH * F2]
                           float* __restrict__ gcnt) { // [NGRAPH]
    __shared__ float sW2a[F1 * F2];
    __shared__ float sW2b[F2 * F2];
    __shared__ float sb2a[F2];
    __shared__ float sb2b[F2];
    __shared__ float ls[NGRAPH * F2];
    __shared__ float lc[NGRAPH];
    int t = threadIdx.x;
    for (int i = t; i < F1 * F2; i += blockDim.x) sW2a[i] = W2a[i];
    for (int i = t; i < F2 * F2; i += blockDim.x) sW2b[i] = W2b[i];
    if (t < F2) { sb2a[t] = b2a[t]; sb2b[t] = b2b[t]; }
    for (int i = t; i < NGRAPH * F2; i += blockDim.x) ls[i] = 0.0f;
    if (t < NGRAPH) lc[t] = 0.0f;
    __syncthreads();

    int n = blockIdx.x * blockDim.x + t;
    if (n < N_NODES) {
        float h[F1];
#pragma unroll
        for (int k = 0; k < F1; k++) h[k] = h1[n * F1 + k] + agg2[n * F1 + k];

        float u[F2];
#pragma unroll
        for (int j = 0; j < F2; j++) {
            float s = sb2a[j];
#pragma unroll
            for (int k = 0; k < F1; k++) s += h[k] * sW2a[k * F2 + j];
            u[j] = fmaxf(s, 0.0f);
        }
        float v[F2];
#pragma unroll
        for (int j = 0; j < F2; j++) {
            float s = sb2b[j];
#pragma unroll
            for (int k = 0; k < F2; k++) s += u[k] * sW2b[k * F2 + j];
            v[j] = fmaxf(s, 0.0f);
        }
        int g = batch[n];
#pragma unroll
        for (int j = 0; j < F2; j++) atomicAdd(&ls[g * F2 + j], v[j]);
        atomicAdd(&lc[g], 1.0f);
    }
    __syncthreads();
    // flush block-local partials (post-relu sums are >= 0; 0 entries are no-ops)
    for (int i = t; i < NGRAPH * F2; i += blockDim.x)
        if (ls[i] != 0.0f) atomicAdd(&gsum[i], ls[i]);
    if (t < NGRAPH && lc[t] != 0.0f) atomicAdd(&gcnt[t], lc[t]);
}

// ---------------- final: pooled -> FC -> log_softmax ----------------
__global__ void final_k(const float* __restrict__ gsum,
                        const float* __restrict__ gcnt,
                        const float* __restrict__ Wfc, const float* __restrict__ bfc,
                        float* __restrict__ out) {
    int g = threadIdx.x;
    if (g >= NGRAPH) return;
    float cnt = fmaxf(gcnt[g], 1.0f);
    float p[F2];
#pragma unroll
    for (int f = 0; f < F2; f++) p[f] = gsum[g * F2 + f] / cnt;
    float l[NCLS];
#pragma unroll
    for (int c = 0; c < NCLS; c++) {
        float s = bfc[c];
#pragma unroll
        for (int f = 0; f < F2; f++) s += p[f] * Wfc[f * NCLS + c];
        l[c] = s;
    }
    float m = -INFINITY;
#pragma unroll
    for (int c = 0; c < NCLS; c++) m = fmaxf(m, l[c]);
    float s = 0.0f;
#pragma unroll
    for (int c = 0; c < NCLS; c++) s += expf(l[c] - m);
    float lse = m + logf(s);
#pragma unroll
    for (int c = 0; c < NCLS; c++) out[g * NCLS + c] = l[c] - lse;
}

extern "C" void kernel_launch(void* const* d_in, const int* in_sizes, int n_in,
                              void* d_out, int out_size, void* d_ws, size_t ws_size,
                              hipStream_t stream) {
    const float* x    = (const float*)d_in[0];
    const int*   ei   = (const int*)d_in[1];   // [2, N_EDGES]
    const int*   batch= (const int*)d_in[2];   // [N_NODES]
    const float* W1a  = (const float*)d_in[3];
    const float* b1a  = (const float*)d_in[4];
    const float* W1b  = (const float*)d_in[5];
    const float* b1b  = (const float*)d_in[6];
    const float* W2a  = (const float*)d_in[7];
    const float* b2a  = (const float*)d_in[8];
    const float* W2b  = (const float*)d_in[9];
    const float* b2b  = (const float*)d_in[10];
    const float* Wfc  = (const float*)d_in[11];
    const float* bfc  = (const float*)d_in[12];
    float* out = (float*)d_out;

    // workspace layout (floats)
    float* ws   = (float*)d_ws;
    float* agg1 = ws;                                   // N_NODES*32
    float* h1   = agg1 + (size_t)N_NODES * F0;          // N_NODES*16
    float* agg2 = h1   + (size_t)N_NODES * F1;          // N_NODES*16
    float* gsum = agg2 + (size_t)N_NODES * F1;          // 64*8
    float* gcnt = gsum + NGRAPH * F2;                   // 64

    // zero the accumulators (ws is re-poisoned to 0xAA before every launch)
    hipMemsetAsync(agg1, 0, (size_t)N_NODES * F0 * sizeof(float), stream);
    hipMemsetAsync(agg2, 0, (size_t)N_NODES * F1 * sizeof(float), stream);
    hipMemsetAsync(gsum, 0, (NGRAPH * F2 + NGRAPH) * sizeof(float), stream);

    {
        int total = N_EDGES * F0;
        scatter32_k<<<(total + 255) / 256, 256, 0, stream>>>(x, ei, agg1);
    }
    mlp1_k<<<(N_NODES + 255) / 256, 256, 0, stream>>>(x, agg1, W1a, b1a, W1b, b1b, h1);
    {
        int total = N_EDGES * F1;
        scatter16_k<<<(total + 255) / 256, 256, 0, stream>>>(h1, ei, agg2);
    }
    mlp2pool_k<<<(N_NODES + 255) / 256, 256, 0, stream>>>(h1, agg2, W2a, b2a, W2b, b2b,
                                                          batch, gsum, gcnt);
    final_k<<<1, 64, 0, stream>>>(gsum, gcnt, Wfc, bfc, out);
}

// Round 2
// 279.635 us; speedup vs baseline: 1.3279x; 1.3279x over previous
//
#include <hip/hip_runtime.h>
#include <hip/hip_bf16.h>
#include <math.h>

#define N_NODES 100000
#define N_EDGES 1600000
#define F0 32
#define F1 16
#define F2 8
#define NCLS 6
#define NGRAPH 64

// ---- xform1: xw1 = x @ W1a  (32 -> 16, no bias/relu; linearity lets us
//      project BEFORE the edge scatter, halving atomic traffic) ----
__global__ void xform1_k(const float* __restrict__ x,
                         const float* __restrict__ W1a,
                         float* __restrict__ xw1) {
    __shared__ float sW[F0 * F1];
    int t = threadIdx.x;
    for (int i = t; i < F0 * F1; i += blockDim.x) sW[i] = W1a[i];
    __syncthreads();
    int n = blockIdx.x * blockDim.x + t;
    if (n >= N_NODES) return;
    float xi[F0];
#pragma unroll
    for (int k = 0; k < F0; k++) xi[k] = x[n * F0 + k];
#pragma unroll
    for (int j = 0; j < F1; j++) {
        float s = 0.0f;
#pragma unroll
        for (int k = 0; k < F0; k++) s += xi[k] * sW[k * F1 + j];
        xw1[n * F1 + j] = s;
    }
}

// ---- scatter 16 features: agg[dst] += xw1[src] ----
__global__ void scatter_f16_k(const float* __restrict__ v,
                              const int* __restrict__ ei,
                              float* __restrict__ agg) {
    int tid = blockIdx.x * blockDim.x + threadIdx.x;
    int e = tid >> 4;
    int f = tid & 15;
    if (e >= N_EDGES) return;
    int src = ei[e];
    int dst = ei[N_EDGES + e];
    atomicAdd(&agg[dst * F1 + f], v[src * F1 + f]);
}

// ---- scatter 8 features: agg[dst] += h1w[src] ----
__global__ void scatter_f8_k(const float* __restrict__ v,
                             const int* __restrict__ ei,
                             float* __restrict__ agg) {
    int tid = blockIdx.x * blockDim.x + threadIdx.x;
    int e = tid >> 3;
    int f = tid & 7;
    if (e >= N_EDGES) return;
    int src = ei[e];
    int dst = ei[N_EDGES + e];
    atomicAdd(&agg[dst * F2 + f], v[src * F2 + f]);
}

// ---- mlp1b: u = relu(xw1 + agg1w + b1a); h1 = relu(u@W1b + b1b);
//      h1w = h1 @ W2a (16 -> 8, projected for the next scatter) ----
__global__ void mlp1b_k(const float* __restrict__ xw1,
                        const float* __restrict__ agg1w,
                        const float* __restrict__ b1a,
                        const float* __restrict__ W1b, const float* __restrict__ b1b,
                        const float* __restrict__ W2a,
                        float* __restrict__ h1w) {
    __shared__ float sW1b[F1 * F1];
    __shared__ float sW2a[F1 * F2];
    __shared__ float sb1a[F1];
    __shared__ float sb1b[F1];
    int t = threadIdx.x;
    for (int i = t; i < F1 * F1; i += blockDim.x) sW1b[i] = W1b[i];
    for (int i = t; i < F1 * F2; i += blockDim.x) sW2a[i] = W2a[i];
    if (t < F1) { sb1a[t] = b1a[t]; sb1b[t] = b1b[t]; }
    __syncthreads();

    int n = blockIdx.x * blockDim.x + t;
    if (n >= N_NODES) return;

    float u[F1];
#pragma unroll
    for (int k = 0; k < F1; k++)
        u[k] = fmaxf(xw1[n * F1 + k] + agg1w[n * F1 + k] + sb1a[k], 0.0f);

    float h[F1];
#pragma unroll
    for (int j = 0; j < F1; j++) {
        float s = sb1b[j];
#pragma unroll
        for (int k = 0; k < F1; k++) s += u[k] * sW1b[k * F1 + j];
        h[j] = fmaxf(s, 0.0f);   // inner-linear + outer relu (relu∘relu = relu)
    }
#pragma unroll
    for (int j = 0; j < F2; j++) {
        float s = 0.0f;
#pragma unroll
        for (int k = 0; k < F1; k++) s += h[k] * sW2a[k * F2 + j];
        h1w[n * F2 + j] = s;
    }
}

// ---- layer-2 tail fused with mean-pool accumulation (batch sorted) ----
__global__ void mlp2pool_k(const float* __restrict__ h1w,
                           const float* __restrict__ agg2w,
                           const float* __restrict__ b2a,
                           const float* __restrict__ W2b, const float* __restrict__ b2b,
                           const int* __restrict__ batch,
                           float* __restrict__ gsum,   // [NGRAPH * F2]
                           float* __restrict__ gcnt) { // [NGRAPH]
    __shared__ float sW2b[F2 * F2];
    __shared__ float sb2a[F2];
    __shared__ float sb2b[F2];
    __shared__ float ls[NGRAPH * F2];
    __shared__ float lc[NGRAPH];
    int t = threadIdx.x;
    for (int i = t; i < F2 * F2; i += blockDim.x) sW2b[i] = W2b[i];
    if (t < F2) { sb2a[t] = b2a[t]; sb2b[t] = b2b[t]; }
    for (int i = t; i < NGRAPH * F2; i += blockDim.x) ls[i] = 0.0f;
    if (t < NGRAPH) lc[t] = 0.0f;
    __syncthreads();

    int n = blockIdx.x * blockDim.x + t;
    if (n < N_NODES) {
        float u[F2];
#pragma unroll
        for (int k = 0; k < F2; k++)
            u[k] = fmaxf(h1w[n * F2 + k] + agg2w[n * F2 + k] + sb2a[k], 0.0f);

        float v[F2];
#pragma unroll
        for (int j = 0; j < F2; j++) {
            float s = sb2b[j];
#pragma unroll
            for (int k = 0; k < F2; k++) s += u[k] * sW2b[k * F2 + j];
            v[j] = fmaxf(s, 0.0f);
        }
        int g = batch[n];
#pragma unroll
        for (int j = 0; j < F2; j++) atomicAdd(&ls[g * F2 + j], v[j]);
        atomicAdd(&lc[g], 1.0f);
    }
    __syncthreads();
    for (int i = t; i < NGRAPH * F2; i += blockDim.x)
        if (ls[i] != 0.0f) atomicAdd(&gsum[i], ls[i]);
    if (t < NGRAPH && lc[t] != 0.0f) atomicAdd(&gcnt[t], lc[t]);
}

// ---------------- final: pooled -> FC -> log_softmax ----------------
__global__ void final_k(const float* __restrict__ gsum,
                        const float* __restrict__ gcnt,
                        const float* __restrict__ Wfc, const float* __restrict__ bfc,
                        float* __restrict__ out) {
    int g = threadIdx.x;
    if (g >= NGRAPH) return;
    float cnt = fmaxf(gcnt[g], 1.0f);
    float p[F2];
#pragma unroll
    for (int f = 0; f < F2; f++) p[f] = gsum[g * F2 + f] / cnt;
    float l[NCLS];
#pragma unroll
    for (int c = 0; c < NCLS; c++) {
        float s = bfc[c];
#pragma unroll
        for (int f = 0; f < F2; f++) s += p[f] * Wfc[f * NCLS + c];
        l[c] = s;
    }
    float m = -INFINITY;
#pragma unroll
    for (int c = 0; c < NCLS; c++) m = fmaxf(m, l[c]);
    float s = 0.0f;
#pragma unroll
    for (int c = 0; c < NCLS; c++) s += expf(l[c] - m);
    float lse = m + logf(s);
#pragma unroll
    for (int c = 0; c < NCLS; c++) out[g * NCLS + c] = l[c] - lse;
}

extern "C" void kernel_launch(void* const* d_in, const int* in_sizes, int n_in,
                              void* d_out, int out_size, void* d_ws, size_t ws_size,
                              hipStream_t stream) {
    const float* x    = (const float*)d_in[0];
    const int*   ei   = (const int*)d_in[1];   // [2, N_EDGES]
    const int*   batch= (const int*)d_in[2];   // [N_NODES]
    const float* W1a  = (const float*)d_in[3];
    const float* b1a  = (const float*)d_in[4];
    const float* W1b  = (const float*)d_in[5];
    const float* b1b  = (const float*)d_in[6];
    const float* W2a  = (const float*)d_in[7];
    const float* b2a  = (const float*)d_in[8];
    const float* W2b  = (const float*)d_in[9];
    const float* b2b  = (const float*)d_in[10];
    const float* Wfc  = (const float*)d_in[11];
    const float* bfc  = (const float*)d_in[12];
    float* out = (float*)d_out;

    // workspace layout (floats) — agg buffers adjacent for one memset
    float* ws    = (float*)d_ws;
    float* agg1w = ws;                                   // N_NODES*16
    float* agg2w = agg1w + (size_t)N_NODES * F1;         // N_NODES*8
    float* xw1   = agg2w + (size_t)N_NODES * F2;         // N_NODES*16
    float* h1w   = xw1   + (size_t)N_NODES * F1;         // N_NODES*8
    float* gsum  = h1w   + (size_t)N_NODES * F2;         // 64*8
    float* gcnt  = gsum  + NGRAPH * F2;                  // 64

    hipMemsetAsync(agg1w, 0, (size_t)N_NODES * (F1 + F2) * sizeof(float), stream);
    hipMemsetAsync(gsum, 0, (NGRAPH * F2 + NGRAPH) * sizeof(float), stream);

    xform1_k<<<(N_NODES + 255) / 256, 256, 0, stream>>>(x, W1a, xw1);
    {
        int total = N_EDGES * F1;
        scatter_f16_k<<<(total + 255) / 256, 256, 0, stream>>>(xw1, ei, agg1w);
    }
    mlp1b_k<<<(N_NODES + 255) / 256, 256, 0, stream>>>(xw1, agg1w, b1a, W1b, b1b, W2a, h1w);
    {
        int total = N_EDGES * F2;
        scatter_f8_k<<<(total + 255) / 256, 256, 0, stream>>>(h1w, ei, agg2w);
    }
    mlp2pool_k<<<(N_NODES + 255) / 256, 256, 0, stream>>>(h1w, agg2w, b2a, W2b, b2b,
                                                          batch, gsum, gcnt);
    final_k<<<1, 64, 0, stream>>>(gsum, gcnt, Wfc, bfc, out);
}